// Round 9
// baseline (220.939 us; speedup 1.0000x reference)
//
#include <hip/hip_runtime.h>

#define B_   1024
#define L_   2048
#define IND_ 64
#define H_   4
#define K_   64

// ---------------- prep 1: wefT[b][j][h][e] = (1/4) * sum_d q[b,h,d] * Wh[4j+e, h*16+d]
// (transposed layout: lane j of a 16-lane group loads wefT[b][j][0..15] = 64 B)
__global__ __launch_bounds__(64) void prep_weff_k(const float* __restrict__ target,
                                                  const float* __restrict__ Wq,
                                                  const float* __restrict__ Wh,
                                                  float* __restrict__ wefT) {
  const int b = blockIdx.x;
  const int t = threadIdx.x;  // weight row index i = 0..63
  __shared__ float tgt[64];
  __shared__ double q[64];
  tgt[t] = target[b * 64 + t];
  __syncthreads();
  double acc = 0.0;
#pragma unroll
  for (int j = 0; j < 64; ++j) acc += (double)tgt[j] * (double)Wq[j * 64 + t];
  q[t] = acc;
  __syncthreads();
#pragma unroll
  for (int h = 0; h < H_; ++h) {
    double a2 = 0.0;
#pragma unroll
    for (int d = 0; d < 16; ++d) a2 += q[h * 16 + d] * (double)Wh[t * 64 + h * 16 + d];
    wefT[((size_t)b << 8) + ((t >> 2) << 4) + (h << 2) + (t & 3)] = (float)(a2 * 0.25);
  }
}

// ---------------- prep 2: M[h][i][j] = sum_d Wv[i, h*16+d] * Wo[h*16+d, j]
__global__ __launch_bounds__(256) void prep_M_k(const float* __restrict__ Wv,
                                                const float* __restrict__ Wo,
                                                float* __restrict__ M) {
  const int idx = blockIdx.x * 256 + threadIdx.x;  // 0..16383
  const int h = idx >> 12, i = (idx >> 6) & 63, j = idx & 63;
  double a = 0.0;
#pragma unroll
  for (int d = 0; d < 16; ++d)
    a += (double)Wv[i * 64 + h * 16 + d] * (double)Wo[(h * 16 + d) * 64 + j];
  M[idx] = (float)a;
}

// monotone float->uint key (order-preserving), and inverse
__device__ __forceinline__ unsigned f2key(float s) {
  unsigned u = __float_as_uint(s);
  return (u & 0x80000000u) ? ~u : (u | 0x80000000u);
}
__device__ __forceinline__ float key2f(unsigned k) {
  unsigned u = (k & 0x80000000u) ? (k & 0x7FFFFFFFu) : ~k;
  return __uint_as_float(u);
}

// DPP move within 16-lane rows; invalid source lanes read 0 (bound_ctrl=true).
// row_shl:N (ctrl 0x100+N): dst[i]=src[i+N] -> sum accumulates into lane 0
// of each 16-lane group (verified rounds 6-8).
template <int CTRL>
__device__ __forceinline__ float dpp_mov(float x) {
  return __int_as_float(
      __builtin_amdgcn_update_dpp(0, __float_as_int(x), CTRL, 0xf, 0xf, true));
}

// ---------------- kernel A: scoring as a GPU-wide SEQUENTIAL sweep ----------
// 2048 blocks x 256 thr. Row-group (4 rows) gi = blockIdx*4 + wave + iter*8192:
// consecutive waves/blocks cover consecutive 1 KB chunks -> the grid sweeps an
// 8 MB window per iteration, sequentially across 64 iterations (fill/copy-like
// DRAM pattern). High occupancy (low VGPR, no min-waves cap) provides TLP.
__global__ __launch_bounds__(256) void score_k(const float* __restrict__ seq,
                                               const float* __restrict__ wefT,
                                               float* __restrict__ scw) {
  const int tid = threadIdx.x;
  const int w = tid >> 6, ln = tid & 63;
  const int g4 = ln >> 4;  // row within 4-row group
  const int j = ln & 15;   // float4 column within row
  const int grp0 = (blockIdx.x << 2) + w;
  const float4* __restrict__ seq4 = reinterpret_cast<const float4*>(seq);
#pragma unroll 2
  for (int i = 0; i < 64; ++i) {
    const int gi = grp0 + (i << 13);          // + i*8192
    const int row = (gi << 2) + g4;           // global row in [0, 2M)
    const int b = row >> 11;
    const float4* __restrict__ wp =
        reinterpret_cast<const float4*>(wefT + ((size_t)b << 8) + (j << 4));
    const float4 w0 = wp[0], w1 = wp[1], w2 = wp[2], w3 = wp[3];  // L1/L2-hot
    const float4 v = seq4[((size_t)row << 4) + j];                // HBM stream
    float p0 = v.x * w0.x; p0 = fmaf(v.y, w0.y, p0); p0 = fmaf(v.z, w0.z, p0); p0 = fmaf(v.w, w0.w, p0);
    float p1 = v.x * w1.x; p1 = fmaf(v.y, w1.y, p1); p1 = fmaf(v.z, w1.z, p1); p1 = fmaf(v.w, w1.w, p1);
    float p2 = v.x * w2.x; p2 = fmaf(v.y, w2.y, p2); p2 = fmaf(v.z, w2.z, p2); p2 = fmaf(v.w, w2.w, p2);
    float p3 = v.x * w3.x; p3 = fmaf(v.y, w3.y, p3); p3 = fmaf(v.z, w3.z, p3); p3 = fmaf(v.w, w3.w, p3);
    p0 += dpp_mov<0x108>(p0); p0 += dpp_mov<0x104>(p0); p0 += dpp_mov<0x102>(p0); p0 += dpp_mov<0x101>(p0);
    p1 += dpp_mov<0x108>(p1); p1 += dpp_mov<0x104>(p1); p1 += dpp_mov<0x102>(p1); p1 += dpp_mov<0x101>(p1);
    p2 += dpp_mov<0x108>(p2); p2 += dpp_mov<0x104>(p2); p2 += dpp_mov<0x102>(p2); p2 += dpp_mov<0x101>(p2);
    p3 += dpp_mov<0x108>(p3); p3 += dpp_mov<0x104>(p3); p3 += dpp_mov<0x102>(p3); p3 += dpp_mov<0x101>(p3);
    if (j == 0) {
      float* __restrict__ sb = scw + ((size_t)b << 13) + (row & 2047);
      sb[0]         = p0;
      sb[1 << 11]   = p1;
      sb[2 << 11]   = p2;
      sb[3 << 11]   = p3;
    }
  }
}

// ---------------- kernel B: selection + gather + epilogue (one block per b)
__global__ __launch_bounds__(256) void attn_sel_k(const float* __restrict__ seq,
                                                  const int* __restrict__ mask,
                                                  const float* __restrict__ scw,
                                                  const float* __restrict__ M,
                                                  float* __restrict__ out) {
  __shared__ int   sidx[H_][K_];
  __shared__ float sw[H_][K_];
  __shared__ float svec[H_][64];
  __shared__ float part[H_][64];

  const int b = blockIdx.x;
  const int tid = threadIdx.x;
  const int w = tid >> 6;   // wave id == head id
  const int ln = tid & 63;
  const float* __restrict__ seqb = seq + (size_t)b * (L_ * IND_);
  const int* __restrict__ maskb = mask + (size_t)b * L_;

  // mask bits for this lane's selection rows (coalesced 256 B per t)
  unsigned mbits = 0;
#pragma unroll
  for (int t = 0; t < 32; ++t) mbits |= (maskb[(t << 6) + ln] ? 1u : 0u) << t;

  // ---------- load this head's scores (coalesced; L3/L2-hot scoreboard) ----
  unsigned kk[32];
  const unsigned KNEG = f2key(-1e9f);
  {
    const float* __restrict__ sb = scw + ((size_t)b << 13) + (w << 11);
#pragma unroll
    for (int t = 0; t < 32; ++t) {
      const float s_ = sb[(t << 6) + ln];
      kk[t] = ((mbits >> t) & 1u) ? f2key(s_) : KNEG;
    }
  }

  // ---------- selection: exact 64th-largest via bitwise binary search ------
  unsigned kmax = 0u;
#pragma unroll
  for (int q = 0; q < 32; ++q) kmax = max(kmax, kk[q]);
#pragma unroll
  for (int off = 32; off >= 1; off >>= 1)
    kmax = max(kmax, (unsigned)__shfl_xor((int)kmax, off, 64));
  const float smax = key2f(kmax);

  unsigned lo = 0u, hi = 0xFFFFFFFFu;
  while (lo < hi) {  // find max t with count(key >= t) >= 64
    const unsigned span = hi - lo;
    const unsigned mid = lo + (span >> 1) + (span & 1u);
    int c = 0;
#pragma unroll
    for (int q = 0; q < 32; ++q) c += (kk[q] >= mid) ? 1 : 0;
#pragma unroll
    for (int off = 32; off >= 1; off >>= 1) c += __shfl_xor(c, off, 64);
    if (c >= K_) lo = mid; else hi = mid - 1;
  }
  const unsigned V = lo;
  int cg = 0;
#pragma unroll
  for (int q = 0; q < 32; ++q) cg += (kk[q] > V) ? 1 : 0;
#pragma unroll
  for (int off = 32; off >= 1; off >>= 1) cg += __shfl_xor(cg, off, 64);
  const int m = K_ - cg;  // #ties (==V) to take, lowest index first (lax.top_k stable)

  {
    const unsigned long long lmlt = (1ull << ln) - 1ull;
    int gbase = 0, etaken = 0;
#pragma unroll
    for (int q = 0; q < 32; ++q) {
      const unsigned key = kk[q];
      const int l = ln + (q << 6);  // lane order == index order within chunk
      const bool gt = key > V;
      const bool eq = key == V;
      const unsigned long long bgt = __ballot(gt);
      const unsigned long long beq = __ballot(eq);
      if (gt) {
        const int pos = gbase + __popcll(bgt & lmlt);
        sidx[w][pos] = l;
        sw[w][pos] = expf(key2f(key) - smax);
      }
      const int navail = __popcll(beq);
      const int take = min(m - etaken, navail);
      if (eq) {
        const int rk = __popcll(beq & lmlt);
        if (rk < take) {
          const int pos = 63 - (etaken + rk);  // ties fill from the back
          sidx[w][pos] = l;
          sw[w][pos] = expf(key2f(key) - smax);
        }
      }
      gbase += __popcll(bgt);
      etaken += take;
    }
  }
  // no barrier: sidx/sw written and read by the same wave

  // ---------- gather + softmax-weighted sum of raw seq rows ----------
  {
    const int cg4 = ln & 15;  // float4 column group
    const int rg = ln >> 4;   // row subgroup 0..3
    float4 sv = make_float4(0.f, 0.f, 0.f, 0.f);
    float z = 0.f;
#pragma unroll
    for (int q = 0; q < 16; ++q) {
      const int sl = (q << 2) + rg;
      const int idx = sidx[w][sl];
      const float wt = sw[w][sl];
      const float4 v =
          *reinterpret_cast<const float4*>(seqb + (size_t)idx * 64 + (cg4 << 2));
      sv.x = fmaf(wt, v.x, sv.x);
      sv.y = fmaf(wt, v.y, sv.y);
      sv.z = fmaf(wt, v.z, sv.z);
      sv.w = fmaf(wt, v.w, sv.w);
      z += wt;
    }
#pragma unroll
    for (int off = 16; off <= 32; off <<= 1) {
      sv.x += __shfl_xor(sv.x, off, 64);
      sv.y += __shfl_xor(sv.y, off, 64);
      sv.z += __shfl_xor(sv.z, off, 64);
      sv.w += __shfl_xor(sv.w, off, 64);
      z += __shfl_xor(z, off, 64);
    }
    if (rg == 0) {  // lanes 0..15 hold the reduced result
      const float inv = 1.f / z;
      svec[w][(cg4 << 2) + 0] = sv.x * inv;
      svec[w][(cg4 << 2) + 1] = sv.y * inv;
      svec[w][(cg4 << 2) + 2] = sv.z * inv;
      svec[w][(cg4 << 2) + 3] = sv.w * inv;
    }
  }
  __syncthreads();

  // ---------- epilogue: out[b,:] = sum_h svec_h @ M_h ----------
  {
    float o = 0.f;
    const float* __restrict__ Mh = M + (w << 12);
#pragma unroll
    for (int i = 0; i < 64; ++i) o = fmaf(svec[w][i], Mh[(i << 6) + ln], o);
    part[w][ln] = o;
  }
  __syncthreads();
  if (tid < 64)
    out[(size_t)b * 64 + tid] = part[0][tid] + part[1][tid] + part[2][tid] + part[3][tid];
}

extern "C" void kernel_launch(void* const* d_in, const int* in_sizes, int n_in,
                              void* d_out, int out_size, void* d_ws, size_t ws_size,
                              hipStream_t stream) {
  const float* target = (const float*)d_in[0];
  const float* seq    = (const float*)d_in[1];
  const int*   mask   = (const int*)d_in[2];
  const float* Wq     = (const float*)d_in[3];
  const float* Wh     = (const float*)d_in[4];
  const float* Wv     = (const float*)d_in[5];
  const float* Wo     = (const float*)d_in[6];
  float* out  = (float*)d_out;
  float* wefT = (float*)d_ws;                    // B*256 floats = 1 MB
  float* M    = wefT + (size_t)B_ * 256;         // 64 KB
  float* scw  = M + (size_t)H_ * 64 * 64;        // B*H*L floats = 32 MB

  prep_weff_k<<<B_, 64, 0, stream>>>(target, Wq, Wh, wefT);
  prep_M_k<<<64, 256, 0, stream>>>(Wv, Wo, M);
  score_k<<<2048, 256, 0, stream>>>(seq, wefT, scw);
  attn_sel_k<<<B_, 256, 0, stream>>>(seq, mask, scw, M, out);
}

// Round 10
// 133.196 us; speedup vs baseline: 1.6587x; 1.6587x over previous
//
#include <hip/hip_runtime.h>

#define B_   1024
#define L_   2048
#define IND_ 64
#define H_   4
#define K_   64

// ---------------- prep 1: w_eff[b][h][i] = (1/4) * sum_d q[b,h,d] * Wh[i, h*16+d]
__global__ __launch_bounds__(64) void prep_weff_k(const float* __restrict__ target,
                                                  const float* __restrict__ Wq,
                                                  const float* __restrict__ Wh,
                                                  float* __restrict__ weff) {
  const int b = blockIdx.x;
  const int t = threadIdx.x;  // 0..63
  __shared__ float tgt[64];
  __shared__ double q[64];
  tgt[t] = target[b * 64 + t];
  __syncthreads();
  double acc = 0.0;
#pragma unroll
  for (int j = 0; j < 64; ++j) acc += (double)tgt[j] * (double)Wq[j * 64 + t];
  q[t] = acc;
  __syncthreads();
#pragma unroll
  for (int h = 0; h < H_; ++h) {
    double a2 = 0.0;
#pragma unroll
    for (int d = 0; d < 16; ++d) a2 += q[h * 16 + d] * (double)Wh[t * 64 + h * 16 + d];
    weff[((size_t)b * H_ + h) * 64 + t] = (float)(a2 * 0.25);  // fold 1/SCALE
  }
}

// ---------------- prep 2: M[h][i][j] = sum_d Wv[i, h*16+d] * Wo[h*16+d, j]
__global__ __launch_bounds__(256) void prep_M_k(const float* __restrict__ Wv,
                                                const float* __restrict__ Wo,
                                                float* __restrict__ M) {
  const int idx = blockIdx.x * 256 + threadIdx.x;  // 0..16383
  const int h = idx >> 12, i = (idx >> 6) & 63, j = idx & 63;
  double a = 0.0;
#pragma unroll
  for (int d = 0; d < 16; ++d)
    a += (double)Wv[i * 64 + h * 16 + d] * (double)Wo[(h * 16 + d) * 64 + j];
  M[idx] = (float)a;
}

// monotone float->uint key (order-preserving), and inverse
__device__ __forceinline__ unsigned f2key(float s) {
  unsigned u = __float_as_uint(s);
  return (u & 0x80000000u) ? ~u : (u | 0x80000000u);
}
__device__ __forceinline__ float key2f(unsigned k) {
  unsigned u = (k & 0x80000000u) ? (k & 0x7FFFFFFFu) : ~k;
  return __uint_as_float(u);
}

// DPP cross-lane move (bound_ctrl=true: invalid -> 0).
// quad_perm 0xB1 = [1,0,3,2] (xor 1); 0x4E = [2,3,0,1] (xor 2).
template <int CTRL>
__device__ __forceinline__ float dpp_f(float x) {
  return __int_as_float(
      __builtin_amdgcn_update_dpp(0, __float_as_int(x), CTRL, 0xf, 0xf, true));
}
// ds_swizzle BitMode xor: offset = (xor<<10) | 0x1F. LDS pipe (offloads VALU).
template <int OFF>
__device__ __forceinline__ float swz_f(float x) {
  return __int_as_float(__builtin_amdgcn_ds_swizzle(__float_as_int(x), OFF));
}

// ---------------- main kernel: one block per b; 4 waves
// Phase 1 (barrier-free): wave w streams rows [512w, 512w+512) scoring ALL 4
// heads; pipelined 8-deep double-buffered loads (R8). Reduce = head-
// interleaved butterfly (lane j ends with head j&3's sum): ~29 inst/row vs
// R8's ~50 -> lifts the VALU ceiling from ~5.6 to ~10 TB/s (R8 was
// VALU-issue-bound, which is why deeper pipelining stalled at 137 us).
__global__ __launch_bounds__(256, 4) void attn_main_k(const float* __restrict__ seq,
                                                      const int* __restrict__ mask,
                                                      const float* __restrict__ weff,
                                                      const float* __restrict__ M,
                                                      float* __restrict__ out) {
  __shared__ float scores[L_ * H_];  // 32 KB, layout [row][h]
  __shared__ int   sidx[H_][K_];
  __shared__ float sw[H_][K_];
  __shared__ float svec[H_][64];
  __shared__ float part[H_][64];

  const int b = blockIdx.x;
  const int tid = threadIdx.x;
  const int w = tid >> 6;   // wave id (phase1: row slice; later: head id)
  const int ln = tid & 63;
  const int g = ln >> 4;    // row subgroup 0..3
  const int j = ln & 15;    // float4 column index
  const float* __restrict__ seqb = seq + (size_t)b * (L_ * IND_);
  const int* __restrict__ maskb = mask + (size_t)b * L_;
  const bool b1 = (ln & 1) != 0;
  const bool b2 = (ln & 2) != 0;

  // per-lane wef fragment: wefv[h][e] = weff[b][h][4j+e]  (16 VGPRs)
  float wefv[H_][4];
  {
    const float* wp = weff + (size_t)b * (H_ * 64) + (j << 2);
#pragma unroll
    for (int h = 0; h < H_; ++h) {
      const float4 v = *reinterpret_cast<const float4*>(wp + (h << 6));
      wefv[h][0] = v.x; wefv[h][1] = v.y; wefv[h][2] = v.z; wefv[h][3] = v.w;
    }
  }

  // ---------- phase 1: scoring, zero barriers, pipelined 8-deep batches ----
  const int rbase = (w << 9) + g;  // this lane's first row
  const float4* __restrict__ lp4 =
      reinterpret_cast<const float4*>(seqb) + (rbase << 4) + j;

  float4 vvA[8], vvB[8];

#define LOADB(V, SB)                                                          \
  {                                                                           \
    _Pragma("unroll") for (int u = 0; u < 8; ++u)                             \
        V[u] = lp4[(((SB) << 3) + u) << 6];                                   \
  }
#define COMPUTE(V, SB)                                                        \
  {                                                                           \
    _Pragma("unroll") for (int u = 0; u < 8; ++u) {                           \
      const int s = ((SB) << 3) + u;                                          \
      const float4 v = V[u];                                                  \
      float p0 = v.x * wefv[0][0]; p0 = fmaf(v.y, wefv[0][1], p0);            \
      p0 = fmaf(v.z, wefv[0][2], p0); p0 = fmaf(v.w, wefv[0][3], p0);         \
      float p1 = v.x * wefv[1][0]; p1 = fmaf(v.y, wefv[1][1], p1);            \
      p1 = fmaf(v.z, wefv[1][2], p1); p1 = fmaf(v.w, wefv[1][3], p1);         \
      float p2 = v.x * wefv[2][0]; p2 = fmaf(v.y, wefv[2][1], p2);            \
      p2 = fmaf(v.z, wefv[2][2], p2); p2 = fmaf(v.w, wefv[2][3], p2);         \
      float p3 = v.x * wefv[3][0]; p3 = fmaf(v.y, wefv[3][1], p3);            \
      p3 = fmaf(v.z, wefv[3][2], p3); p3 = fmaf(v.w, wefv[3][3], p3);         \
      /* head-interleaved butterfly over the 16-lane group */                 \
      const float a  = (b1 ? p1 : p0) + dpp_f<0xB1>(b1 ? p0 : p1);            \
      const float bb = (b1 ? p3 : p2) + dpp_f<0xB1>(b1 ? p2 : p3);            \
      float c = (b2 ? bb : a) + dpp_f<0x4E>(b2 ? a : bb);                     \
      c += swz_f<0x101F>(c); /* xor 4 */                                      \
      c += swz_f<0x201F>(c); /* xor 8 */                                      \
      if (j < 4) scores[((rbase + (s << 2)) << 2) + j] = c;                   \
    }                                                                         \
  }

  LOADB(vvA, 0);
  LOADB(vvB, 1);  COMPUTE(vvA, 0);
  LOADB(vvA, 2);  COMPUTE(vvB, 1);
  LOADB(vvB, 3);  COMPUTE(vvA, 2);
  LOADB(vvA, 4);  COMPUTE(vvB, 3);
  LOADB(vvB, 5);  COMPUTE(vvA, 4);
  LOADB(vvA, 6);  COMPUTE(vvB, 5);
  LOADB(vvB, 7);  COMPUTE(vvA, 6);
  LOADB(vvA, 8);  COMPUTE(vvB, 7);
  LOADB(vvB, 9);  COMPUTE(vvA, 8);
  LOADB(vvA, 10); COMPUTE(vvB, 9);
  LOADB(vvB, 11); COMPUTE(vvA, 10);
  LOADB(vvA, 12); COMPUTE(vvB, 11);
  LOADB(vvB, 13); COMPUTE(vvA, 12);
  LOADB(vvA, 14); COMPUTE(vvB, 13);
  LOADB(vvB, 15); COMPUTE(vvA, 14);
                  COMPUTE(vvB, 15);
#undef LOADB
#undef COMPUTE

  // mask bits for this lane's selection rows
  unsigned mbits = 0;
#pragma unroll
  for (int t = 0; t < 32; ++t) mbits |= (maskb[(t << 6) + ln] ? 1u : 0u) << t;

  __syncthreads();  // scoreboard complete; wave w now owns head w

  // ---------- selection: exact 64th-largest via bitwise binary search ------
  unsigned kk[32];
  const unsigned KNEG = f2key(-1e9f);
#pragma unroll
  for (int t = 0; t < 32; ++t) {
    const float s_ = scores[(((t << 6) + ln) << 2) + w];
    kk[t] = ((mbits >> t) & 1u) ? f2key(s_) : KNEG;
  }

  unsigned kmax = 0u;
#pragma unroll
  for (int q = 0; q < 32; ++q) kmax = max(kmax, kk[q]);
#pragma unroll
  for (int off = 32; off >= 1; off >>= 1)
    kmax = max(kmax, (unsigned)__shfl_xor((int)kmax, off, 64));
  const float smax = key2f(kmax);

  unsigned lo = 0u, hi = 0xFFFFFFFFu;
  while (lo < hi) {  // find max t with count(key >= t) >= 64
    const unsigned span = hi - lo;
    const unsigned mid = lo + (span >> 1) + (span & 1u);
    int c = 0;
#pragma unroll
    for (int q = 0; q < 32; ++q) c += (kk[q] >= mid) ? 1 : 0;
#pragma unroll
    for (int off = 32; off >= 1; off >>= 1) c += __shfl_xor(c, off, 64);
    if (c >= K_) lo = mid; else hi = mid - 1;
  }
  const unsigned V = lo;
  int cg = 0;
#pragma unroll
  for (int q = 0; q < 32; ++q) cg += (kk[q] > V) ? 1 : 0;
#pragma unroll
  for (int off = 32; off >= 1; off >>= 1) cg += __shfl_xor(cg, off, 64);
  const int m = K_ - cg;  // #ties (==V) to take, lowest index first (lax.top_k stable)

  {
    const unsigned long long lmlt = (1ull << ln) - 1ull;
    int gbase = 0, etaken = 0;
#pragma unroll
    for (int q = 0; q < 32; ++q) {
      const unsigned key = kk[q];
      const int l = ln + (q << 6);  // lane order == index order within chunk
      const bool gt = key > V;
      const bool eq = key == V;
      const unsigned long long bgt = __ballot(gt);
      const unsigned long long beq = __ballot(eq);
      if (gt) {
        const int pos = gbase + __popcll(bgt & lmlt);
        sidx[w][pos] = l;
        sw[w][pos] = expf(key2f(key) - smax);
      }
      const int navail = __popcll(beq);
      const int take = min(m - etaken, navail);
      if (eq) {
        const int rk = __popcll(beq & lmlt);
        if (rk < take) {
          const int pos = 63 - (etaken + rk);  // ties fill from the back
          sidx[w][pos] = l;
          sw[w][pos] = expf(key2f(key) - smax);
        }
      }
      gbase += __popcll(bgt);
      etaken += take;
    }
  }
  // no barrier: sidx/sw written and read by the same wave

  // ---------- gather + softmax-weighted sum of raw seq rows ----------
  {
    const int cg4 = ln & 15;  // float4 column group
    const int rg = ln >> 4;   // row subgroup 0..3
    float4 sv = make_float4(0.f, 0.f, 0.f, 0.f);
    float z = 0.f;
#pragma unroll
    for (int q = 0; q < 16; ++q) {
      const int sl = (q << 2) + rg;
      const int idx = sidx[w][sl];
      const float wt = sw[w][sl];
      const float4 v =
          *reinterpret_cast<const float4*>(seqb + (size_t)idx * 64 + (cg4 << 2));
      sv.x = fmaf(wt, v.x, sv.x);
      sv.y = fmaf(wt, v.y, sv.y);
      sv.z = fmaf(wt, v.z, sv.z);
      sv.w = fmaf(wt, v.w, sv.w);
      z += wt;
    }
#pragma unroll
    for (int off = 16; off <= 32; off <<= 1) {
      sv.x += __shfl_xor(sv.x, off, 64);
      sv.y += __shfl_xor(sv.y, off, 64);
      sv.z += __shfl_xor(sv.z, off, 64);
      sv.w += __shfl_xor(sv.w, off, 64);
      z += __shfl_xor(z, off, 64);
    }
    if (rg == 0) {  // lanes 0..15 hold the reduced result
      const float inv = 1.f / z;
      svec[w][(cg4 << 2) + 0] = sv.x * inv;
      svec[w][(cg4 << 2) + 1] = sv.y * inv;
      svec[w][(cg4 << 2) + 2] = sv.z * inv;
      svec[w][(cg4 << 2) + 3] = sv.w * inv;
    }
  }
  __syncthreads();

  // ---------- epilogue: out[b,:] = sum_h svec_h @ M_h ----------
  {
    float o = 0.f;
    const float* __restrict__ Mh = M + (w << 12);
#pragma unroll
    for (int i = 0; i < 64; ++i) o = fmaf(svec[w][i], Mh[(i << 6) + ln], o);
    part[w][ln] = o;
  }
  __syncthreads();
  if (tid < 64)
    out[(size_t)b * 64 + tid] = part[0][tid] + part[1][tid] + part[2][tid] + part[3][tid];
}

extern "C" void kernel_launch(void* const* d_in, const int* in_sizes, int n_in,
                              void* d_out, int out_size, void* d_ws, size_t ws_size,
                              hipStream_t stream) {
  const float* target = (const float*)d_in[0];
  const float* seq    = (const float*)d_in[1];
  const int*   mask   = (const int*)d_in[2];
  const float* Wq     = (const float*)d_in[3];
  const float* Wh     = (const float*)d_in[4];
  const float* Wv     = (const float*)d_in[5];
  const float* Wo     = (const float*)d_in[6];
  float* out  = (float*)d_out;
  float* weff = (float*)d_ws;                   // B*H*64 floats = 1 MB
  float* M    = weff + (size_t)B_ * H_ * 64;    // H*64*64 floats = 64 KB

  prep_weff_k<<<B_, 64, 0, stream>>>(target, Wq, Wh, weff);
  prep_M_k<<<64, 256, 0, stream>>>(Wv, Wo, M);
  attn_main_k<<<B_, 256, 0, stream>>>(seq, mask, weff, M, out);
}

// Round 11
// 127.982 us; speedup vs baseline: 1.7263x; 1.0407x over previous
//
#include <hip/hip_runtime.h>

#define B_   1024
#define L_   2048
#define IND_ 64
#define H_   4
#define K_   64

// ---------------- prep 1: w_eff[b][h][i] = (1/4) * sum_d q[b,h,d] * Wh[i, h*16+d]
__global__ __launch_bounds__(64) void prep_weff_k(const float* __restrict__ target,
                                                  const float* __restrict__ Wq,
                                                  const float* __restrict__ Wh,
                                                  float* __restrict__ weff) {
  const int b = blockIdx.x;
  const int t = threadIdx.x;  // 0..63
  __shared__ float tgt[64];
  __shared__ double q[64];
  tgt[t] = target[b * 64 + t];
  __syncthreads();
  double acc = 0.0;
#pragma unroll
  for (int j = 0; j < 64; ++j) acc += (double)tgt[j] * (double)Wq[j * 64 + t];
  q[t] = acc;
  __syncthreads();
#pragma unroll
  for (int h = 0; h < H_; ++h) {
    double a2 = 0.0;
#pragma unroll
    for (int d = 0; d < 16; ++d) a2 += q[h * 16 + d] * (double)Wh[t * 64 + h * 16 + d];
    weff[((size_t)b * H_ + h) * 64 + t] = (float)(a2 * 0.25);  // fold 1/SCALE
  }
}

// ---------------- prep 2: M[h][i][j] = sum_d Wv[i, h*16+d] * Wo[h*16+d, j]
__global__ __launch_bounds__(256) void prep_M_k(const float* __restrict__ Wv,
                                                const float* __restrict__ Wo,
                                                float* __restrict__ M) {
  const int idx = blockIdx.x * 256 + threadIdx.x;  // 0..16383
  const int h = idx >> 12, i = (idx >> 6) & 63, j = idx & 63;
  double a = 0.0;
#pragma unroll
  for (int d = 0; d < 16; ++d)
    a += (double)Wv[i * 64 + h * 16 + d] * (double)Wo[(h * 16 + d) * 64 + j];
  M[idx] = (float)a;
}

// monotone float->uint key (order-preserving), and inverse
__device__ __forceinline__ unsigned f2key(float s) {
  unsigned u = __float_as_uint(s);
  return (u & 0x80000000u) ? ~u : (u | 0x80000000u);
}
__device__ __forceinline__ float key2f(unsigned k) {
  unsigned u = (k & 0x80000000u) ? (k & 0x7FFFFFFFu) : ~k;
  return __uint_as_float(u);
}

// DPP cross-lane move (bound_ctrl=true: invalid -> 0).
// quad_perm 0xB1 = [1,0,3,2] (xor 1); 0x4E = [2,3,0,1] (xor 2).
template <int CTRL>
__device__ __forceinline__ float dpp_f(float x) {
  return __int_as_float(
      __builtin_amdgcn_update_dpp(0, __float_as_int(x), CTRL, 0xf, 0xf, true));
}
// ds_swizzle BitMode xor: offset = (xor<<10) | 0x1F. LDS pipe (offloads VALU).
template <int OFF>
__device__ __forceinline__ float swz_f(float x) {
  return __int_as_float(__builtin_amdgcn_ds_swizzle(__float_as_int(x), OFF));
}

// ---------------- main kernel: one block per b; 4 waves
// Phase 1: WAVE-INTERLEAVED streaming. Step s: wave w covers rows
// [s*16 + 4w, s*16 + 4w + 4) -> the block's 4 waves form ONE contiguous
// 4 KB/step moving window (1024 chunky GPU-wide streams instead of 4096
// scattered 128 KB slabs; R10's ~4.8 TB/s is attributed to DRAM page
// thrash from stream count). Pipelined 8-deep double-buffered loads (R8),
// head-interleaved butterfly reduce (R10, verified).
__global__ __launch_bounds__(256, 4) void attn_main_k(const float* __restrict__ seq,
                                                      const int* __restrict__ mask,
                                                      const float* __restrict__ weff,
                                                      const float* __restrict__ M,
                                                      float* __restrict__ out) {
  __shared__ float scores[L_ * H_];  // 32 KB, layout [row][h]
  __shared__ int   sidx[H_][K_];
  __shared__ float sw[H_][K_];
  __shared__ float svec[H_][64];
  __shared__ float part[H_][64];

  const int b = blockIdx.x;
  const int tid = threadIdx.x;
  const int w = tid >> 6;   // wave id (phase1: interleave slot; later: head id)
  const int ln = tid & 63;
  const int g = ln >> 4;    // row subgroup 0..3
  const int j = ln & 15;    // float4 column index
  const float* __restrict__ seqb = seq + (size_t)b * (L_ * IND_);
  const int* __restrict__ maskb = mask + (size_t)b * L_;
  const bool b1 = (ln & 1) != 0;
  const bool b2 = (ln & 2) != 0;

  // per-lane wef fragment: wefv[h][e] = weff[b][h][4j+e]  (16 VGPRs)
  float wefv[H_][4];
  {
    const float* wp = weff + (size_t)b * (H_ * 64) + (j << 2);
#pragma unroll
    for (int h = 0; h < H_; ++h) {
      const float4 v = *reinterpret_cast<const float4*>(wp + (h << 6));
      wefv[h][0] = v.x; wefv[h][1] = v.y; wefv[h][2] = v.z; wefv[h][3] = v.w;
    }
  }

  // ---------- phase 1: scoring, zero barriers, pipelined 8-deep batches ----
  // lane's float4 base within the block's 4 KB step window:
  //   row = s*16 + w*4 + g, col = j  ->  idx = s*256 + w*64 + g*16 + j
  const float4* __restrict__ lp4 =
      reinterpret_cast<const float4*>(seqb) + (w << 6) + (g << 4) + j;
  const int rb0 = (w << 2) + g;  // row base (without s*16 term)

  float4 vvA[8], vvB[8];

#define LOADB(V, SB)                                                          \
  {                                                                           \
    _Pragma("unroll") for (int u = 0; u < 8; ++u)                             \
        V[u] = lp4[(((SB) << 3) + u) << 8];                                   \
  }
#define COMPUTE(V, SB)                                                        \
  {                                                                           \
    _Pragma("unroll") for (int u = 0; u < 8; ++u) {                           \
      const int s = ((SB) << 3) + u;                                          \
      const float4 v = V[u];                                                  \
      float p0 = v.x * wefv[0][0]; p0 = fmaf(v.y, wefv[0][1], p0);            \
      p0 = fmaf(v.z, wefv[0][2], p0); p0 = fmaf(v.w, wefv[0][3], p0);         \
      float p1 = v.x * wefv[1][0]; p1 = fmaf(v.y, wefv[1][1], p1);            \
      p1 = fmaf(v.z, wefv[1][2], p1); p1 = fmaf(v.w, wefv[1][3], p1);         \
      float p2 = v.x * wefv[2][0]; p2 = fmaf(v.y, wefv[2][1], p2);            \
      p2 = fmaf(v.z, wefv[2][2], p2); p2 = fmaf(v.w, wefv[2][3], p2);         \
      float p3 = v.x * wefv[3][0]; p3 = fmaf(v.y, wefv[3][1], p3);            \
      p3 = fmaf(v.z, wefv[3][2], p3); p3 = fmaf(v.w, wefv[3][3], p3);         \
      /* head-interleaved butterfly over the 16-lane group */                 \
      const float a  = (b1 ? p1 : p0) + dpp_f<0xB1>(b1 ? p0 : p1);            \
      const float bb = (b1 ? p3 : p2) + dpp_f<0xB1>(b1 ? p2 : p3);            \
      float c = (b2 ? bb : a) + dpp_f<0x4E>(b2 ? a : bb);                     \
      c += swz_f<0x101F>(c); /* xor 4 */                                      \
      c += swz_f<0x201F>(c); /* xor 8 */                                      \
      const int row = (s << 4) + rb0;                                         \
      if (j < 4) scores[(row << 2) + j] = c;                                  \
    }                                                                         \
  }

  LOADB(vvA, 0);
  LOADB(vvB, 1);  COMPUTE(vvA, 0);
  LOADB(vvA, 2);  COMPUTE(vvB, 1);
  LOADB(vvB, 3);  COMPUTE(vvA, 2);
  LOADB(vvA, 4);  COMPUTE(vvB, 3);
  LOADB(vvB, 5);  COMPUTE(vvA, 4);
  LOADB(vvA, 6);  COMPUTE(vvB, 5);
  LOADB(vvB, 7);  COMPUTE(vvA, 6);
  LOADB(vvA, 8);  COMPUTE(vvB, 7);
  LOADB(vvB, 9);  COMPUTE(vvA, 8);
  LOADB(vvA, 10); COMPUTE(vvB, 9);
  LOADB(vvB, 11); COMPUTE(vvA, 10);
  LOADB(vvA, 12); COMPUTE(vvB, 11);
  LOADB(vvB, 13); COMPUTE(vvA, 12);
  LOADB(vvA, 14); COMPUTE(vvB, 13);
  LOADB(vvB, 15); COMPUTE(vvA, 14);
                  COMPUTE(vvB, 15);
#undef LOADB
#undef COMPUTE

  // mask bits for this lane's selection rows
  unsigned mbits = 0;
#pragma unroll
  for (int t = 0; t < 32; ++t) mbits |= (maskb[(t << 6) + ln] ? 1u : 0u) << t;

  __syncthreads();  // scoreboard complete; wave w now owns head w

  // ---------- selection: exact 64th-largest via bitwise binary search ------
  unsigned kk[32];
  const unsigned KNEG = f2key(-1e9f);
#pragma unroll
  for (int t = 0; t < 32; ++t) {
    const float s_ = scores[(((t << 6) + ln) << 2) + w];
    kk[t] = ((mbits >> t) & 1u) ? f2key(s_) : KNEG;
  }

  unsigned kmax = 0u;
#pragma unroll
  for (int q = 0; q < 32; ++q) kmax = max(kmax, kk[q]);
#pragma unroll
  for (int off = 32; off >= 1; off >>= 1)
    kmax = max(kmax, (unsigned)__shfl_xor((int)kmax, off, 64));
  const float smax = key2f(kmax);

  unsigned lo = 0u, hi = 0xFFFFFFFFu;
  while (lo < hi) {  // find max t with count(key >= t) >= 64
    const unsigned span = hi - lo;
    const unsigned mid = lo + (span >> 1) + (span & 1u);
    int c = 0;
#pragma unroll
    for (int q = 0; q < 32; ++q) c += (kk[q] >= mid) ? 1 : 0;
#pragma unroll
    for (int off = 32; off >= 1; off >>= 1) c += __shfl_xor(c, off, 64);
    if (c >= K_) lo = mid; else hi = mid - 1;
  }
  const unsigned V = lo;
  int cg = 0;
#pragma unroll
  for (int q = 0; q < 32; ++q) cg += (kk[q] > V) ? 1 : 0;
#pragma unroll
  for (int off = 32; off >= 1; off >>= 1) cg += __shfl_xor(cg, off, 64);
  const int m = K_ - cg;  // #ties (==V) to take, lowest index first (lax.top_k stable)

  {
    const unsigned long long lmlt = (1ull << ln) - 1ull;
    int gbase = 0, etaken = 0;
#pragma unroll
    for (int q = 0; q < 32; ++q) {
      const unsigned key = kk[q];
      const int l = ln + (q << 6);  // lane order == index order within chunk
      const bool gt = key > V;
      const bool eq = key == V;
      const unsigned long long bgt = __ballot(gt);
      const unsigned long long beq = __ballot(eq);
      if (gt) {
        const int pos = gbase + __popcll(bgt & lmlt);
        sidx[w][pos] = l;
        sw[w][pos] = expf(key2f(key) - smax);
      }
      const int navail = __popcll(beq);
      const int take = min(m - etaken, navail);
      if (eq) {
        const int rk = __popcll(beq & lmlt);
        if (rk < take) {
          const int pos = 63 - (etaken + rk);  // ties fill from the back
          sidx[w][pos] = l;
          sw[w][pos] = expf(key2f(key) - smax);
        }
      }
      gbase += __popcll(bgt);
      etaken += take;
    }
  }
  // no barrier: sidx/sw written and read by the same wave

  // ---------- gather + softmax-weighted sum of raw seq rows ----------
  {
    const int cg4 = ln & 15;  // float4 column group
    const int rg = ln >> 4;   // row subgroup 0..3
    float4 sv = make_float4(0.f, 0.f, 0.f, 0.f);
    float z = 0.f;
#pragma unroll
    for (int q = 0; q < 16; ++q) {
      const int sl = (q << 2) + rg;
      const int idx = sidx[w][sl];
      const float wt = sw[w][sl];
      const float4 v =
          *reinterpret_cast<const float4*>(seqb + (size_t)idx * 64 + (cg4 << 2));
      sv.x = fmaf(wt, v.x, sv.x);
      sv.y = fmaf(wt, v.y, sv.y);
      sv.z = fmaf(wt, v.z, sv.z);
      sv.w = fmaf(wt, v.w, sv.w);
      z += wt;
    }
#pragma unroll
    for (int off = 16; off <= 32; off <<= 1) {
      sv.x += __shfl_xor(sv.x, off, 64);
      sv.y += __shfl_xor(sv.y, off, 64);
      sv.z += __shfl_xor(sv.z, off, 64);
      sv.w += __shfl_xor(sv.w, off, 64);
      z += __shfl_xor(z, off, 64);
    }
    if (rg == 0) {  // lanes 0..15 hold the reduced result
      const float inv = 1.f / z;
      svec[w][(cg4 << 2) + 0] = sv.x * inv;
      svec[w][(cg4 << 2) + 1] = sv.y * inv;
      svec[w][(cg4 << 2) + 2] = sv.z * inv;
      svec[w][(cg4 << 2) + 3] = sv.w * inv;
    }
  }
  __syncthreads();

  // ---------- epilogue: out[b,:] = sum_h svec_h @ M_h ----------
  {
    float o = 0.f;
    const float* __restrict__ Mh = M + (w << 12);
#pragma unroll
    for (int i = 0; i < 64; ++i) o = fmaf(svec[w][i], Mh[(i << 6) + ln], o);
    part[w][ln] = o;
  }
  __syncthreads();
  if (tid < 64)
    out[(size_t)b * 64 + tid] = part[0][tid] + part[1][tid] + part[2][tid] + part[3][tid];
}

extern "C" void kernel_launch(void* const* d_in, const int* in_sizes, int n_in,
                              void* d_out, int out_size, void* d_ws, size_t ws_size,
                              hipStream_t stream) {
  const float* target = (const float*)d_in[0];
  const float* seq    = (const float*)d_in[1];
  const int*   mask   = (const int*)d_in[2];
  const float* Wq     = (const float*)d_in[3];
  const float* Wh     = (const float*)d_in[4];
  const float* Wv     = (const float*)d_in[5];
  const float* Wo     = (const float*)d_in[6];
  float* out  = (float*)d_out;
  float* weff = (float*)d_ws;                   // B*H*64 floats = 1 MB
  float* M    = weff + (size_t)B_ * H_ * 64;    // H*64*64 floats = 64 KB

  prep_weff_k<<<B_, 64, 0, stream>>>(target, Wq, Wh, weff);
  prep_M_k<<<64, 256, 0, stream>>>(Wv, Wo, M);
  attn_main_k<<<B_, 256, 0, stream>>>(seq, mask, weff, M, out);
}